// Round 1
// baseline (384.468 us; speedup 1.0000x reference)
//
#include <hip/hip_runtime.h>
#include <math.h>

#define BATCH 4
#define SPATIAL (64*64*64)   // D*H*W = 262144
#define NCH 64
#define NB 512               // partial-reduction blocks per batch

__device__ __forceinline__ float sigmoidf_(float z) { return 1.f / (1.f + expf(-z)); }

// ---------------- Kernel A: partial spatial sum/max per (b, chunk, c) ----------------
__global__ __launch_bounds__(256) void pool_partial_kernel(
    const float* __restrict__ x, float* __restrict__ psum, float* __restrict__ pmax) {
  const int b     = blockIdx.x / NB;
  const int chunk = blockIdx.x % NB;
  const int tid  = threadIdx.x;
  const int w    = tid >> 6;          // wave in block (0..3)
  const int lane = tid & 63;
  const int q    = lane >> 4;         // position-in-group (0..3)
  const int g    = lane & 15;         // channel group (4 ch each)

  const float4* xb = (const float4*)x + (size_t)b * SPATIAL * 16;
  float s0=0.f, s1=0.f, s2=0.f, s3=0.f;
  float m0=-INFINITY, m1=-INFINITY, m2=-INFINITY, m3=-INFINITY;

  const int PPB = SPATIAL / NB;       // 512 positions per block
  #pragma unroll 4
  for (int i = 0; i < PPB / 16; ++i) {  // 16 positions per block-iteration
    int p = chunk * PPB + i * 16 + w * 4 + q;
    float4 v = xb[(size_t)p * 16 + g];
    s0 += v.x; s1 += v.y; s2 += v.z; s3 += v.w;
    m0 = fmaxf(m0, v.x); m1 = fmaxf(m1, v.y); m2 = fmaxf(m2, v.z); m3 = fmaxf(m3, v.w);
  }
  // reduce across the 4 position-slots q (lanes xor 16, 32 keep same g)
  #pragma unroll
  for (int mask = 16; mask <= 32; mask <<= 1) {
    s0 += __shfl_xor(s0, mask); s1 += __shfl_xor(s1, mask);
    s2 += __shfl_xor(s2, mask); s3 += __shfl_xor(s3, mask);
    m0 = fmaxf(m0, __shfl_xor(m0, mask)); m1 = fmaxf(m1, __shfl_xor(m1, mask));
    m2 = fmaxf(m2, __shfl_xor(m2, mask)); m3 = fmaxf(m3, __shfl_xor(m3, mask));
  }
  __shared__ float lsum[4][64];
  __shared__ float lmax[4][64];
  if (q == 0) {
    lsum[w][g*4+0] = s0; lsum[w][g*4+1] = s1; lsum[w][g*4+2] = s2; lsum[w][g*4+3] = s3;
    lmax[w][g*4+0] = m0; lmax[w][g*4+1] = m1; lmax[w][g*4+2] = m2; lmax[w][g*4+3] = m3;
  }
  __syncthreads();
  if (tid < 64) {
    float s = lsum[0][tid] + lsum[1][tid] + lsum[2][tid] + lsum[3][tid];
    float m = fmaxf(fmaxf(lmax[0][tid], lmax[1][tid]), fmaxf(lmax[2][tid], lmax[3][tid]));
    psum[((size_t)b * NB + chunk) * 64 + tid] = s;
    pmax[((size_t)b * NB + chunk) * 64 + tid] = m;
  }
}

// ---------------- Kernel B: finalize pools + MLP -> ca[B][C] ----------------
__global__ __launch_bounds__(256) void ca_kernel(
    const float* __restrict__ psum, const float* __restrict__ pmax,
    const float* __restrict__ w1, const float* __restrict__ b1,
    const float* __restrict__ w2, const float* __restrict__ b2,
    float* __restrict__ ca) {
  const int tid = threadIdx.x;
  const int b = tid >> 6, c = tid & 63;   // wave per batch, lane per channel
  float s = 0.f, m = -INFINITY;
  #pragma unroll 8
  for (int k = 0; k < NB; ++k) {
    s += psum[((size_t)b * NB + k) * 64 + c];
    m = fmaxf(m, pmax[((size_t)b * NB + k) * 64 + c]);
  }
  float avg = s * (1.f / SPATIAL);

  float w1c[4];
  #pragma unroll
  for (int j = 0; j < 4; ++j) w1c[j] = w1[c * 4 + j];
  float pa[4], pm[4];
  #pragma unroll
  for (int j = 0; j < 4; ++j) { pa[j] = avg * w1c[j]; pm[j] = m * w1c[j]; }
  #pragma unroll
  for (int mask = 1; mask < 64; mask <<= 1) {
    #pragma unroll
    for (int j = 0; j < 4; ++j) {
      pa[j] += __shfl_xor(pa[j], mask);
      pm[j] += __shfl_xor(pm[j], mask);
    }
  }
  float za = b2[c], zm = b2[c];
  #pragma unroll
  for (int j = 0; j < 4; ++j) {
    float ha = fmaxf(pa[j] + b1[j], 0.f);
    float hm = fmaxf(pm[j] + b1[j], 0.f);
    za += ha * w2[j * 64 + c];
    zm += hm * w2[j * 64 + c];
  }
  ca[b * 64 + c] = sigmoidf_(za) + sigmoidf_(zm);
}

// ---------------- Kernel C: per-voxel channel mean/max of x*ca -> sp[B*S][2] ----------------
__global__ __launch_bounds__(256) void spstats_kernel(
    const float* __restrict__ x, const float* __restrict__ ca, float* __restrict__ sp) {
  const int tid = threadIdx.x, lane = tid & 63, w = tid >> 6;
  const int q = lane >> 4, g = lane & 15;
  const int waveId = blockIdx.x * 4 + w;
  const int nWaves = gridDim.x * 4;
  const int NGRP = BATCH * SPATIAL / 4;
  const float4* x4  = (const float4*)x;
  const float4* ca4 = (const float4*)ca;
  for (int grp = waveId; grp < NGRP; grp += nWaves) {
    int p = grp * 4 + q;          // global voxel index
    int b = p >> 18;              // / SPATIAL
    float4 v  = x4[(size_t)p * 16 + g];
    float4 cv = ca4[b * 16 + g];
    float ax = v.x * cv.x, ay = v.y * cv.y, az = v.z * cv.z, aw = v.w * cv.w;
    float s = ax + ay + az + aw;
    float m = fmaxf(fmaxf(ax, ay), fmaxf(az, aw));
    #pragma unroll
    for (int mask = 1; mask < 16; mask <<= 1) {
      s += __shfl_xor(s, mask);
      m = fmaxf(m, __shfl_xor(m, mask));
    }
    if (g == 0) {
      float2 o; o.x = s * (1.f / 64.f); o.y = m;
      ((float2*)sp)[p] = o;
    }
  }
}

// ---------------- Kernel D: 7x7x7x2 conv + sigmoid -> sa[B*S] ----------------
__global__ __launch_bounds__(256) void conv_kernel(
    const float* __restrict__ sp, const float* __restrict__ cw, float* __restrict__ sa) {
  __shared__ float wsh[686];
  for (int i = threadIdx.x; i < 686; i += 256) wsh[i] = cw[i];
  __syncthreads();
  const int bid = blockIdx.x;
  const int ygrp = bid & 15, z = (bid >> 4) & 63, b = bid >> 10;
  const int xc = threadIdx.x & 63;
  const int y = (ygrp << 2) + (threadIdx.x >> 6);
  const float2* spb = (const float2*)sp + (size_t)b * SPATIAL;
  float acc = 0.f;
  for (int kz = 0; kz < 7; ++kz) {
    int zi = z + kz - 3;
    if ((unsigned)zi >= 64u) continue;
    for (int ky = 0; ky < 7; ++ky) {
      int yi = y + ky - 3;
      if ((unsigned)yi >= 64u) continue;
      const float2* row  = spb + ((zi << 6) + yi) * 64;
      const float*  wrow = wsh + ((kz * 7 + ky) * 7) * 2;
      #pragma unroll
      for (int kx = 0; kx < 7; ++kx) {
        int xi = xc + kx - 3;
        if ((unsigned)xi < 64u) {
          float2 v = row[xi];
          acc = fmaf(v.x, wrow[kx * 2 + 0], acc);
          acc = fmaf(v.y, wrow[kx * 2 + 1], acc);
        }
      }
    }
  }
  sa[(((size_t)b * 64 + z) * 64 + y) * 64 + xc] = sigmoidf_(acc);
}

// ---------------- Kernel E: out = x * ca * sa ----------------
__global__ __launch_bounds__(256) void final_kernel(
    const float* __restrict__ x, const float* __restrict__ ca,
    const float* __restrict__ sa, float* __restrict__ out) {
  const int tid = threadIdx.x, lane = tid & 63, w = tid >> 6;
  const int q = lane >> 4, g = lane & 15;
  const int waveId = blockIdx.x * 4 + w;
  const int nWaves = gridDim.x * 4;
  const int NGRP = BATCH * SPATIAL / 4;
  const float4* x4  = (const float4*)x;
  const float4* ca4 = (const float4*)ca;
  float4* o4 = (float4*)out;
  for (int grp = waveId; grp < NGRP; grp += nWaves) {
    int p = grp * 4 + q;
    int b = p >> 18;
    float4 v  = x4[(size_t)p * 16 + g];
    float4 cv = ca4[b * 16 + g];
    float sv = sa[p];
    float4 o;
    o.x = v.x * cv.x * sv; o.y = v.y * cv.y * sv;
    o.z = v.z * cv.z * sv; o.w = v.w * cv.w * sv;
    o4[(size_t)p * 16 + g] = o;
  }
}

extern "C" void kernel_launch(void* const* d_in, const int* in_sizes, int n_in,
                              void* d_out, int out_size, void* d_ws, size_t ws_size,
                              hipStream_t stream) {
  const float* x  = (const float*)d_in[0];
  const float* w1 = (const float*)d_in[1];
  const float* b1 = (const float*)d_in[2];
  const float* w2 = (const float*)d_in[3];
  const float* b2 = (const float*)d_in[4];
  const float* cw = (const float*)d_in[5];
  float* out = (float*)d_out;
  float* ws  = (float*)d_ws;

  // workspace layout (floats)
  float* ca   = ws;                                  // 256
  float* psum = ws + 256;                            // BATCH*NB*64 = 131072
  float* pmax = psum + (size_t)BATCH * NB * 64;      // 131072
  float* sp   = pmax + (size_t)BATCH * NB * 64;      // BATCH*SPATIAL*2 = 2097152
  float* sa   = sp + (size_t)BATCH * SPATIAL * 2;    // BATCH*SPATIAL  = 1048576

  pool_partial_kernel<<<BATCH * NB, 256, 0, stream>>>(x, psum, pmax);
  ca_kernel<<<1, 256, 0, stream>>>(psum, pmax, w1, b1, w2, b2, ca);
  spstats_kernel<<<2048, 256, 0, stream>>>(x, ca, sp);
  conv_kernel<<<BATCH * 64 * 16, 256, 0, stream>>>(sp, cw, sa);
  final_kernel<<<2048, 256, 0, stream>>>(x, ca, sa, out);
}

// Round 2
// 291.792 us; speedup vs baseline: 1.3176x; 1.3176x over previous
//
#include <hip/hip_runtime.h>
#include <math.h>

#define BATCH 4
#define SPATIAL (64*64*64)   // D*H*W = 262144
#define NCH 64
#define NB 512               // partial-reduction blocks per batch

__device__ __forceinline__ float sigmoidf_(float z) { return 1.f / (1.f + expf(-z)); }

// ---------------- Kernel A: partial spatial sum/max per (b, chunk, c) ----------------
__global__ __launch_bounds__(256) void pool_partial_kernel(
    const float* __restrict__ x, float* __restrict__ psum, float* __restrict__ pmax) {
  const int b     = blockIdx.x / NB;
  const int chunk = blockIdx.x % NB;
  const int tid  = threadIdx.x;
  const int w    = tid >> 6;          // wave in block (0..3)
  const int lane = tid & 63;
  const int q    = lane >> 4;         // position-in-group (0..3)
  const int g    = lane & 15;         // channel group (4 ch each)

  const float4* xb = (const float4*)x + (size_t)b * SPATIAL * 16;
  float s0=0.f, s1=0.f, s2=0.f, s3=0.f;
  float m0=-INFINITY, m1=-INFINITY, m2=-INFINITY, m3=-INFINITY;

  const int PPB = SPATIAL / NB;       // 512 positions per block
  #pragma unroll 4
  for (int i = 0; i < PPB / 16; ++i) {  // 16 positions per block-iteration
    int p = chunk * PPB + i * 16 + w * 4 + q;
    float4 v = xb[(size_t)p * 16 + g];
    s0 += v.x; s1 += v.y; s2 += v.z; s3 += v.w;
    m0 = fmaxf(m0, v.x); m1 = fmaxf(m1, v.y); m2 = fmaxf(m2, v.z); m3 = fmaxf(m3, v.w);
  }
  // reduce across the 4 position-slots q (lanes xor 16, 32 keep same g)
  #pragma unroll
  for (int mask = 16; mask <= 32; mask <<= 1) {
    s0 += __shfl_xor(s0, mask); s1 += __shfl_xor(s1, mask);
    s2 += __shfl_xor(s2, mask); s3 += __shfl_xor(s3, mask);
    m0 = fmaxf(m0, __shfl_xor(m0, mask)); m1 = fmaxf(m1, __shfl_xor(m1, mask));
    m2 = fmaxf(m2, __shfl_xor(m2, mask)); m3 = fmaxf(m3, __shfl_xor(m3, mask));
  }
  __shared__ float lsum[4][64];
  __shared__ float lmax[4][64];
  if (q == 0) {
    lsum[w][g*4+0] = s0; lsum[w][g*4+1] = s1; lsum[w][g*4+2] = s2; lsum[w][g*4+3] = s3;
    lmax[w][g*4+0] = m0; lmax[w][g*4+1] = m1; lmax[w][g*4+2] = m2; lmax[w][g*4+3] = m3;
  }
  __syncthreads();
  if (tid < 64) {
    float s = lsum[0][tid] + lsum[1][tid] + lsum[2][tid] + lsum[3][tid];
    float m = fmaxf(fmaxf(lmax[0][tid], lmax[1][tid]), fmaxf(lmax[2][tid], lmax[3][tid]));
    psum[((size_t)b * NB + chunk) * 64 + tid] = s;
    pmax[((size_t)b * NB + chunk) * 64 + tid] = m;
  }
}

// ---------------- Kernel B: finalize pools + MLP -> ca[B][C] ----------------
__global__ __launch_bounds__(256) void ca_kernel(
    const float* __restrict__ psum, const float* __restrict__ pmax,
    const float* __restrict__ w1, const float* __restrict__ b1,
    const float* __restrict__ w2, const float* __restrict__ b2,
    float* __restrict__ ca) {
  const int tid = threadIdx.x;
  const int b = tid >> 6, c = tid & 63;   // wave per batch, lane per channel
  float s = 0.f, m = -INFINITY;
  #pragma unroll 8
  for (int k = 0; k < NB; ++k) {
    s += psum[((size_t)b * NB + k) * 64 + c];
    m = fmaxf(m, pmax[((size_t)b * NB + k) * 64 + c]);
  }
  float avg = s * (1.f / SPATIAL);

  float w1c[4];
  #pragma unroll
  for (int j = 0; j < 4; ++j) w1c[j] = w1[c * 4 + j];
  float pa[4], pm[4];
  #pragma unroll
  for (int j = 0; j < 4; ++j) { pa[j] = avg * w1c[j]; pm[j] = m * w1c[j]; }
  #pragma unroll
  for (int mask = 1; mask < 64; mask <<= 1) {
    #pragma unroll
    for (int j = 0; j < 4; ++j) {
      pa[j] += __shfl_xor(pa[j], mask);
      pm[j] += __shfl_xor(pm[j], mask);
    }
  }
  float za = b2[c], zm = b2[c];
  #pragma unroll
  for (int j = 0; j < 4; ++j) {
    float ha = fmaxf(pa[j] + b1[j], 0.f);
    float hm = fmaxf(pm[j] + b1[j], 0.f);
    za += ha * w2[j * 64 + c];
    zm += hm * w2[j * 64 + c];
  }
  ca[b * 64 + c] = sigmoidf_(za) + sigmoidf_(zm);
}

// ---------------- Kernel C: per-voxel channel mean/max of x*ca -> sp[B*S][2] ----------------
__global__ __launch_bounds__(256) void spstats_kernel(
    const float* __restrict__ x, const float* __restrict__ ca, float* __restrict__ sp) {
  const int tid = threadIdx.x, lane = tid & 63, w = tid >> 6;
  const int q = lane >> 4, g = lane & 15;
  const int waveId = blockIdx.x * 4 + w;
  const int nWaves = gridDim.x * 4;
  const int NGRP = BATCH * SPATIAL / 4;
  const float4* x4  = (const float4*)x;
  const float4* ca4 = (const float4*)ca;
  for (int grp = waveId; grp < NGRP; grp += nWaves) {
    int p = grp * 4 + q;          // global voxel index
    int b = p >> 18;              // / SPATIAL
    float4 v  = x4[(size_t)p * 16 + g];
    float4 cv = ca4[b * 16 + g];
    float ax = v.x * cv.x, ay = v.y * cv.y, az = v.z * cv.z, aw = v.w * cv.w;
    float s = ax + ay + az + aw;
    float m = fmaxf(fmaxf(ax, ay), fmaxf(az, aw));
    #pragma unroll
    for (int mask = 1; mask < 16; mask <<= 1) {
      s += __shfl_xor(s, mask);
      m = fmaxf(m, __shfl_xor(m, mask));
    }
    if (g == 0) {
      float2 o; o.x = s * (1.f / 64.f); o.y = m;
      ((float2*)sp)[p] = o;
    }
  }
}

// ---------------- Kernel D: LDS-tiled 7x7x7x2 conv + sigmoid -> sa[B*S] ----------------
// Tile: x = 0..63 (lanes), YT=2 y's, ZT=8 z's per block.
// LDS: 14 planes (z halo) x 8 rows (y halo) x 70 float2 (x halo) = 62720 B.
// Thread (xc = tid&63, ty = tid>>6): computes 2y x 2z outputs (z pair = ty*2+{0,1}).
#define CZT 8
#define CYT 2
#define CPL (CZT + 6)     // 14
#define CRW (CYT + 6)     // 8
#define CXW 70
__global__ __launch_bounds__(256) void conv_kernel(
    const float* __restrict__ sp, const float* __restrict__ cw, float* __restrict__ sa) {
  __shared__ float2 tile[CPL * CRW * CXW];   // 62720 B

  const int bid = blockIdx.x;
  const int zg = bid & 7;           // 8 z-groups
  const int yg = (bid >> 3) & 31;   // 32 y-groups
  const int b  = bid >> 8;
  const int z0 = zg * CZT;
  const int y0 = yg * CYT;

  const float2* spb = (const float2*)sp + (size_t)b * SPATIAL;

  // ---- stage halo tile (zero-filled at volume boundaries) ----
  const int NE = CPL * CRW * CXW;   // 7840
  for (int e = threadIdx.x; e < NE; e += 256) {
    int pl  = e / (CRW * CXW);
    int rem = e - pl * (CRW * CXW);
    int row = rem / CXW;
    int xi  = rem - row * CXW;
    int z = z0 + pl - 3;
    int y = y0 + row - 3;
    int x = xi - 3;
    float2 v = make_float2(0.f, 0.f);
    if ((unsigned)z < 64u && (unsigned)y < 64u && (unsigned)x < 64u)
      v = spb[(z << 12) + (y << 6) + x];
    tile[e] = v;
  }
  __syncthreads();

  const int xc = threadIdx.x & 63;
  const int ty = threadIdx.x >> 6;
  const int zb = ty * 2;            // thread's z-pair base (relative)

  float acc[2][2] = {{0.f, 0.f}, {0.f, 0.f}};   // [dz][dy]

  for (int pp = 0; pp < 8; ++pp) {  // planes zb..zb+7 relative
    const int pl = zb + pp;
    #pragma unroll
    for (int ry = 0; ry < 8; ++ry) {
      const float2* rowp = tile + (pl * CRW + ry) * CXW + xc;
      float fx[7], fy[7];
      #pragma unroll
      for (int k = 0; k < 7; ++k) { float2 v = rowp[k]; fx[k] = v.x; fy[k] = v.y; }
      #pragma unroll
      for (int dz = 0; dz < 2; ++dz) {
        const int kz = pp - dz;
        if ((unsigned)kz > 6u) continue;   // uniform branch
        #pragma unroll
        for (int dy = 0; dy < 2; ++dy) {
          const int ky = ry - dy;
          if ((unsigned)ky > 6u) continue; // compile-time for ry ends
          const float* wp = cw + (kz * 49 + ky * 7) * 2;
          float a = acc[dz][dy];
          #pragma unroll
          for (int kx = 0; kx < 7; ++kx)
            a = fmaf(fx[kx], wp[kx * 2], fmaf(fy[kx], wp[kx * 2 + 1], a));
          acc[dz][dy] = a;
        }
      }
    }
  }

  #pragma unroll
  for (int dz = 0; dz < 2; ++dz) {
    int z = z0 + zb + dz;
    #pragma unroll
    for (int dy = 0; dy < 2; ++dy) {
      int y = y0 + dy;
      sa[(((size_t)b * 64 + z) * 64 + y) * 64 + xc] = sigmoidf_(acc[dz][dy]);
    }
  }
}

// ---------------- Kernel E: out = x * ca * sa ----------------
__global__ __launch_bounds__(256) void final_kernel(
    const float* __restrict__ x, const float* __restrict__ ca,
    const float* __restrict__ sa, float* __restrict__ out) {
  const int tid = threadIdx.x, lane = tid & 63, w = tid >> 6;
  const int q = lane >> 4, g = lane & 15;
  const int waveId = blockIdx.x * 4 + w;
  const int nWaves = gridDim.x * 4;
  const int NGRP = BATCH * SPATIAL / 4;
  const float4* x4  = (const float4*)x;
  const float4* ca4 = (const float4*)ca;
  float4* o4 = (float4*)out;
  for (int grp = waveId; grp < NGRP; grp += nWaves) {
    int p = grp * 4 + q;
    int b = p >> 18;
    float4 v  = x4[(size_t)p * 16 + g];
    float4 cv = ca4[b * 16 + g];
    float sv = sa[p];
    float4 o;
    o.x = v.x * cv.x * sv; o.y = v.y * cv.y * sv;
    o.z = v.z * cv.z * sv; o.w = v.w * cv.w * sv;
    o4[(size_t)p * 16 + g] = o;
  }
}

extern "C" void kernel_launch(void* const* d_in, const int* in_sizes, int n_in,
                              void* d_out, int out_size, void* d_ws, size_t ws_size,
                              hipStream_t stream) {
  const float* x  = (const float*)d_in[0];
  const float* w1 = (const float*)d_in[1];
  const float* b1 = (const float*)d_in[2];
  const float* w2 = (const float*)d_in[3];
  const float* b2 = (const float*)d_in[4];
  const float* cw = (const float*)d_in[5];
  float* out = (float*)d_out;
  float* ws  = (float*)d_ws;

  // workspace layout (floats)
  float* ca   = ws;                                  // 256
  float* psum = ws + 256;                            // BATCH*NB*64 = 131072
  float* pmax = psum + (size_t)BATCH * NB * 64;      // 131072
  float* sp   = pmax + (size_t)BATCH * NB * 64;      // BATCH*SPATIAL*2 = 2097152
  float* sa   = sp + (size_t)BATCH * SPATIAL * 2;    // BATCH*SPATIAL  = 1048576

  pool_partial_kernel<<<BATCH * NB, 256, 0, stream>>>(x, psum, pmax);
  ca_kernel<<<1, 256, 0, stream>>>(psum, pmax, w1, b1, w2, b2, ca);
  spstats_kernel<<<2048, 256, 0, stream>>>(x, ca, sp);
  conv_kernel<<<BATCH * 32 * 8, 256, 0, stream>>>(sp, cw, sa);
  final_kernel<<<2048, 256, 0, stream>>>(x, ca, sa, out);
}

// Round 3
// 231.677 us; speedup vs baseline: 1.6595x; 1.2595x over previous
//
#include <hip/hip_runtime.h>
#include <math.h>

#define BATCH 4
#define SPATIAL (64*64*64)   // D*H*W = 262144
#define NCH 64
#define NB 512               // partial-reduction blocks per batch

typedef float f32x4 __attribute__((ext_vector_type(4)));

__device__ __forceinline__ float sigmoidf_(float z) { return 1.f / (1.f + expf(-z)); }

// ---------------- Kernel A: partial spatial sum/max per (b, chunk, c) ----------------
__global__ __launch_bounds__(256) void pool_partial_kernel(
    const float* __restrict__ x, float* __restrict__ psum, float* __restrict__ pmax) {
  const int b     = blockIdx.x / NB;
  const int chunk = blockIdx.x % NB;
  const int tid  = threadIdx.x;
  const int w    = tid >> 6;          // wave in block (0..3)
  const int lane = tid & 63;
  const int q    = lane >> 4;         // position-in-group (0..3)
  const int g    = lane & 15;         // channel group (4 ch each)

  const float4* xb = (const float4*)x + (size_t)b * SPATIAL * 16;
  float s0=0.f, s1=0.f, s2=0.f, s3=0.f;
  float m0=-INFINITY, m1=-INFINITY, m2=-INFINITY, m3=-INFINITY;

  const int PPB = SPATIAL / NB;       // 512 positions per block
  #pragma unroll 4
  for (int i = 0; i < PPB / 16; ++i) {  // 16 positions per block-iteration
    int p = chunk * PPB + i * 16 + w * 4 + q;
    float4 v = xb[(size_t)p * 16 + g];
    s0 += v.x; s1 += v.y; s2 += v.z; s3 += v.w;
    m0 = fmaxf(m0, v.x); m1 = fmaxf(m1, v.y); m2 = fmaxf(m2, v.z); m3 = fmaxf(m3, v.w);
  }
  // reduce across the 4 position-slots q (lanes xor 16, 32 keep same g)
  #pragma unroll
  for (int mask = 16; mask <= 32; mask <<= 1) {
    s0 += __shfl_xor(s0, mask); s1 += __shfl_xor(s1, mask);
    s2 += __shfl_xor(s2, mask); s3 += __shfl_xor(s3, mask);
    m0 = fmaxf(m0, __shfl_xor(m0, mask)); m1 = fmaxf(m1, __shfl_xor(m1, mask));
    m2 = fmaxf(m2, __shfl_xor(m2, mask)); m3 = fmaxf(m3, __shfl_xor(m3, mask));
  }
  __shared__ float lsum[4][64];
  __shared__ float lmax[4][64];
  if (q == 0) {
    lsum[w][g*4+0] = s0; lsum[w][g*4+1] = s1; lsum[w][g*4+2] = s2; lsum[w][g*4+3] = s3;
    lmax[w][g*4+0] = m0; lmax[w][g*4+1] = m1; lmax[w][g*4+2] = m2; lmax[w][g*4+3] = m3;
  }
  __syncthreads();
  if (tid < 64) {
    float s = lsum[0][tid] + lsum[1][tid] + lsum[2][tid] + lsum[3][tid];
    float m = fmaxf(fmaxf(lmax[0][tid], lmax[1][tid]), fmaxf(lmax[2][tid], lmax[3][tid]));
    psum[((size_t)b * NB + chunk) * 64 + tid] = s;
    pmax[((size_t)b * NB + chunk) * 64 + tid] = m;
  }
}

// ---------------- Kernel B: finalize pools + MLP -> ca[B][C], one block per batch ----------------
__global__ __launch_bounds__(256) void ca_kernel(
    const float* __restrict__ psum, const float* __restrict__ pmax,
    const float* __restrict__ w1, const float* __restrict__ b1,
    const float* __restrict__ w2, const float* __restrict__ b2,
    float* __restrict__ ca) {
  const int b = blockIdx.x;
  const int tid = threadIdx.x;
  const int r = tid >> 6, c = tid & 63;
  float s = 0.f, m = -INFINITY;
  #pragma unroll 4
  for (int k = r; k < NB; k += 4) {
    s += psum[((size_t)b * NB + k) * 64 + c];
    m = fmaxf(m, pmax[((size_t)b * NB + k) * 64 + c]);
  }
  __shared__ float ls[4][64];
  __shared__ float lm[4][64];
  ls[r][c] = s; lm[r][c] = m;
  __syncthreads();
  if (tid < 64) {
    const int cc = tid;
    float ss = ls[0][cc] + ls[1][cc] + ls[2][cc] + ls[3][cc];
    float mm = fmaxf(fmaxf(lm[0][cc], lm[1][cc]), fmaxf(lm[2][cc], lm[3][cc]));
    float avg = ss * (1.f / SPATIAL);

    float w1c[4];
    #pragma unroll
    for (int j = 0; j < 4; ++j) w1c[j] = w1[cc * 4 + j];
    float pa[4], pm[4];
    #pragma unroll
    for (int j = 0; j < 4; ++j) { pa[j] = avg * w1c[j]; pm[j] = mm * w1c[j]; }
    #pragma unroll
    for (int mask = 1; mask < 64; mask <<= 1) {
      #pragma unroll
      for (int j = 0; j < 4; ++j) {
        pa[j] += __shfl_xor(pa[j], mask);
        pm[j] += __shfl_xor(pm[j], mask);
      }
    }
    float za = b2[cc], zm = b2[cc];
    #pragma unroll
    for (int j = 0; j < 4; ++j) {
      float ha = fmaxf(pa[j] + b1[j], 0.f);
      float hm = fmaxf(pm[j] + b1[j], 0.f);
      za += ha * w2[j * 64 + cc];
      zm += hm * w2[j * 64 + cc];
    }
    ca[b * 64 + cc] = sigmoidf_(za) + sigmoidf_(zm);
  }
}

// ---------------- Kernel C: per-voxel channel mean/max of x*ca -> sp[B*S][2] ----------------
__global__ __launch_bounds__(256) void spstats_kernel(
    const float* __restrict__ x, const float* __restrict__ ca, float* __restrict__ sp) {
  const int tid = threadIdx.x, lane = tid & 63, w = tid >> 6;
  const int q = lane >> 4, g = lane & 15;
  const int waveId = blockIdx.x * 4 + w;
  const int nWaves = gridDim.x * 4;
  const int NGRP = BATCH * SPATIAL / 4;
  const float4* x4  = (const float4*)x;
  const float4* ca4 = (const float4*)ca;
  for (int grp = waveId; grp < NGRP; grp += nWaves) {
    int p = grp * 4 + q;          // global voxel index
    int b = p >> 18;              // / SPATIAL
    float4 v  = x4[(size_t)p * 16 + g];
    float4 cv = ca4[b * 16 + g];
    float ax = v.x * cv.x, ay = v.y * cv.y, az = v.z * cv.z, aw = v.w * cv.w;
    float s = ax + ay + az + aw;
    float m = fmaxf(fmaxf(ax, ay), fmaxf(az, aw));
    #pragma unroll
    for (int mask = 1; mask < 16; mask <<= 1) {
      s += __shfl_xor(s, mask);
      m = fmaxf(m, __shfl_xor(m, mask));
    }
    if (g == 0) {
      float2 o; o.x = s * (1.f / 64.f); o.y = m;
      ((float2*)sp)[p] = o;
    }
  }
}

// ---------------- Kernel D: LDS-tiled 7x7x7x2 conv + sigmoid + fused out=x*ca*sa ----------------
// Tile: x = 0..63 (lanes), YT=2 y's, ZT=8 z's per block.
// LDS: 14 planes (z halo) x 8 rows (y halo) x 70 float2 (x halo) = 62720 B.
// After conv, the sa tile (16 rows x 64 x) is stashed into the same LDS and the
// block streams out = x * ca * sa for its 1024 voxels (262 KB read + 262 KB NT write).
#define CZT 8
#define CYT 2
#define CPL (CZT + 6)     // 14
#define CRW (CYT + 6)     // 8
#define CXW 70
__global__ __launch_bounds__(256) void conv_final_kernel(
    const float* __restrict__ sp, const float* __restrict__ cw,
    const float* __restrict__ x, const float* __restrict__ ca,
    float* __restrict__ out) {
  __shared__ float2 tile[CPL * CRW * CXW];   // 62720 B

  const int bid = blockIdx.x;
  const int zg = bid & 7;           // 8 z-groups
  const int yg = (bid >> 3) & 31;   // 32 y-groups
  const int b  = bid >> 8;
  const int z0 = zg * CZT;
  const int y0 = yg * CYT;

  const float2* spb = (const float2*)sp + (size_t)b * SPATIAL;

  // ---- stage halo tile (zero-filled at volume boundaries) ----
  const int NE = CPL * CRW * CXW;   // 7840
  for (int e = threadIdx.x; e < NE; e += 256) {
    int pl  = e / (CRW * CXW);
    int rem = e - pl * (CRW * CXW);
    int row = rem / CXW;
    int xi  = rem - row * CXW;
    int z = z0 + pl - 3;
    int y = y0 + row - 3;
    int xx = xi - 3;
    float2 v = make_float2(0.f, 0.f);
    if ((unsigned)z < 64u && (unsigned)y < 64u && (unsigned)xx < 64u)
      v = spb[(z << 12) + (y << 6) + xx];
    tile[e] = v;
  }
  __syncthreads();

  const int xc = threadIdx.x & 63;
  const int ty = threadIdx.x >> 6;
  const int zb = ty * 2;            // thread's z-pair base (relative)

  float acc[2][2] = {{0.f, 0.f}, {0.f, 0.f}};   // [dz][dy]

  for (int pp = 0; pp < 8; ++pp) {  // planes zb..zb+7 relative
    const int pl = zb + pp;
    #pragma unroll
    for (int ry = 0; ry < 8; ++ry) {
      const float2* rowp = tile + (pl * CRW + ry) * CXW + xc;
      float fx[7], fy[7];
      #pragma unroll
      for (int k = 0; k < 7; ++k) { float2 v = rowp[k]; fx[k] = v.x; fy[k] = v.y; }
      #pragma unroll
      for (int dz = 0; dz < 2; ++dz) {
        const int kz = pp - dz;
        if ((unsigned)kz > 6u) continue;   // uniform branch
        #pragma unroll
        for (int dy = 0; dy < 2; ++dy) {
          const int ky = ry - dy;
          if ((unsigned)ky > 6u) continue; // compile-time for ry ends
          const float* wp = cw + (kz * 49 + ky * 7) * 2;
          float a = acc[dz][dy];
          #pragma unroll
          for (int kx = 0; kx < 7; ++kx)
            a = fmaf(fx[kx], wp[kx * 2], fmaf(fy[kx], wp[kx * 2 + 1], a));
          acc[dz][dy] = a;
        }
      }
    }
  }

  // ---- stash sa tile into LDS (reuse the sp tile buffer) ----
  __syncthreads();                  // all tile reads done
  float* sash = (float*)tile;       // 16 rows x 64 x = 4 KB
  #pragma unroll
  for (int dz = 0; dz < 2; ++dz)
    #pragma unroll
    for (int dy = 0; dy < 2; ++dy)
      sash[((((zb + dz) << 1) | dy) << 6) + xc] = sigmoidf_(acc[dz][dy]);
  __syncthreads();

  // ---- fused final: out = x * ca * sa for this block's 16 (z,y) rows ----
  const float4* x4 = (const float4*)x;
  const float4* ca4 = (const float4*)ca;
  float4 cav = ca4[b * 16 + (threadIdx.x & 15)];
  for (int r = 0; r < 16; ++r) {
    const int z = z0 + (r >> 1);
    const int y = y0 + (r & 1);
    const size_t base4 = ((((size_t)b * 64 + z) * 64 + y)) * 1024;  // float4 units
    #pragma unroll 4
    for (int k = 0; k < 4; ++k) {
      const int f = threadIdx.x + k * 256;        // 0..1023
      const float sv = sash[(r << 6) + (f >> 4)];
      float4 v = x4[base4 + f];
      f32x4 o;
      o.x = v.x * cav.x * sv; o.y = v.y * cav.y * sv;
      o.z = v.z * cav.z * sv; o.w = v.w * cav.w * sv;
      __builtin_nontemporal_store(o, (f32x4*)(out + (base4 + f) * 4));
    }
  }
}

extern "C" void kernel_launch(void* const* d_in, const int* in_sizes, int n_in,
                              void* d_out, int out_size, void* d_ws, size_t ws_size,
                              hipStream_t stream) {
  const float* x  = (const float*)d_in[0];
  const float* w1 = (const float*)d_in[1];
  const float* b1 = (const float*)d_in[2];
  const float* w2 = (const float*)d_in[3];
  const float* b2 = (const float*)d_in[4];
  const float* cw = (const float*)d_in[5];
  float* out = (float*)d_out;
  float* ws  = (float*)d_ws;

  // workspace layout (floats)
  float* ca   = ws;                                  // 256
  float* psum = ws + 256;                            // BATCH*NB*64 = 131072
  float* pmax = psum + (size_t)BATCH * NB * 64;      // 131072
  float* sp   = pmax + (size_t)BATCH * NB * 64;      // BATCH*SPATIAL*2 = 2097152

  pool_partial_kernel<<<BATCH * NB, 256, 0, stream>>>(x, psum, pmax);
  ca_kernel<<<BATCH, 256, 0, stream>>>(psum, pmax, w1, b1, w2, b2, ca);
  spstats_kernel<<<2048, 256, 0, stream>>>(x, ca, sp);
  conv_final_kernel<<<BATCH * 32 * 8, 256, 0, stream>>>(sp, cw, x, ca, out);
}